// Round 7
// baseline (38.716 us; speedup 1.0000x reference)
//
#include <hip/hip_runtime.h>
#include <hip/hip_bf16.h>

// Radon transform: x (4,1,384,384) f32 -> out (4,460,64) f32
// pad = 38, Hp = Wp = 460, N_ANGLES = 64.
//
// R7: R6 (batch-interleaved bf16 texels, one dwordx2 per bilinear corner for
// all 4 batches, normal+transposed layouts in L2) + xx-range split x2 across
// independent blocks (blockIdx.z) with f32 global atomic combine. 14848 waves
// (~2 residency fills) instead of 7424 (<1 fill) -> latency hiding + balance.
// d_out zero-initialized via hipMemsetAsync (graph-capturable memset node).

constexpr int IMG = 384;
constexpr int PAD = 38;
constexpr int P   = 460;   // Hp = Wp
constexpr int NA  = 64;
constexpr int NB  = 4;
constexpr int B_  = 6;               // zero border
constexpr int O_  = PAD - B_;        // 32
constexpr int E_  = IMG + 2 * B_;    // 396
constexpr int NSPLIT = 2;            // xx-range split
constexpr int XCHUNK = P / NSPLIT;   // 230

__device__ __forceinline__ unsigned int f2bfu(float f) {
    __hip_bfloat16 h = __float2bfloat16(f);   // RNE
    return (unsigned int)__builtin_bit_cast(unsigned short, h);
}
__device__ __forceinline__ float bf_lo(unsigned int w) { return __uint_as_float(w << 16); }
__device__ __forceinline__ float bf_hi(unsigned int w) { return __uint_as_float(w & 0xffff0000u); }

// Pad + interleave batches + build normal and transposed layouts.
__global__ __launch_bounds__(256) void pad4_kernel(const float* __restrict__ x,
                                                   uint2* __restrict__ pb,
                                                   uint2* __restrict__ pbT) {
    __shared__ uint2 tile[64][65];
    const int tx = threadIdx.x;          // 0..63
    const int ty = threadIdx.y;          // 0..3
    const int bx = blockIdx.x * 64;
    const int by = blockIdx.y * 64;

    for (int r = ty; r < 64; r += 4) {
        const int iy = by + r, ix = bx + tx;
        const int py = iy - B_, px = ix - B_;       // core coords
        uint2 t = make_uint2(0u, 0u);
        if ((unsigned)py < (unsigned)IMG && (unsigned)px < (unsigned)IMG) {
            const int o = py * IMG + px;
            t.x = f2bfu(x[o])                 | (f2bfu(x[IMG * IMG + o])     << 16);
            t.y = f2bfu(x[2 * IMG * IMG + o]) | (f2bfu(x[3 * IMG * IMG + o]) << 16);
        }
        tile[r][tx] = t;
        if (iy < E_ && ix < E_) pb[iy * E_ + ix] = t;
    }
    __syncthreads();
    for (int r = ty; r < 64; r += 4) {
        const int oy = bx + r;           // transposed row = original col
        const int ox = by + tx;
        if (oy < E_ && ox < E_) pbT[oy * E_ + ox] = tile[tx][r];
    }
}

__global__ __launch_bounds__(256) void radon_kernel(const uint2* __restrict__ pb,
                                                    const uint2* __restrict__ pbT,
                                                    float* __restrict__ out) {
    const int lane = threadIdx.x & 63;
    const int wv   = threadIdx.x >> 6;
    const int l    = lane & 15;              // lane in group
    const int g    = lane >> 4;              // y-group in wave
    const int a    = blockIdx.y;
    const int z    = blockIdx.z;             // xx-chunk
    const int y    = blockIdx.x * 16 + wv * 4 + g;

    const float th = (2.8125f * (float)a) * 0.017453292519943295f;
    float s, c;
    __sincosf(th, &s, &c);

    const float yf = (float)(y < P ? y : P - 1);
    const float ys = (2.0f * yf + 1.0f) / 460.0f - 1.0f;
    // fix = c*xx + A ; fiy = s*xx + By (padded-image pixel coords)
    const float A  = fmaf(-s, ys, 1.0f) * 230.0f - 0.5f - 229.5f * c;
    const float By = fmaf( c, ys, 1.0f) * 230.0f - 0.5f - 229.5f * s;

    // xx-interval where the stencil can touch the core ([36,424] conservative;
    // rcp error + floor slack covered by +/-2 and the 6px border).
    const float rc = __builtin_amdgcn_rcpf(c);
    const float rs = __builtin_amdgcn_rcpf(s);
    float t0 = (36.0f - A) * rc, t1 = (424.0f - A) * rc;
    float lo = fmaxf(0.0f,   fminf(t0, t1));
    float hi = fminf(459.0f, fmaxf(t0, t1));
    t0 = (36.0f - By) * rs; t1 = (424.0f - By) * rs;
    lo = fmaxf(lo, fminf(t0, t1));
    hi = fminf(hi, fmaxf(t0, t1));

    int glo = max(z * XCHUNK, (int)floorf(lo) - 2);
    glo = min(glo, P);                       // saturate +inf case, avoid wrap
    int ghi = min(z * XCHUNK + XCHUNK - 1, (int)ceilf(hi) + 2);
    if (y >= P) { glo = 1; ghi = 0; }

    // Layout: row coord v should step slowly with xx -> |cv| = min(|c|,|s|).
    const bool  useT = fabsf(s) > fabsf(c);
    const float cu = useT ? s  : c;
    const float Au = useT ? By : A;
    const float cv = useT ? c  : s;
    const float Av = useT ? A  : By;
    const uint2* __restrict__ base = useT ? pbT : pb;

    float acc0 = 0.0f, acc1 = 0.0f, acc2 = 0.0f, acc3 = 0.0f;
    float xxf = (float)(glo + l);
    #pragma unroll 2
    for (int xx = glo + l; xx <= ghi; xx += 16, xxf += 16.0f) {
        const float u   = fmaf(cu, xxf, Au);
        const float v   = fmaf(cv, xxf, Av);
        const float u0f = floorf(u);
        const float v0f = floorf(v);
        const float wu  = u - u0f;
        const float wvv = v - v0f;
        const int idx = (int)fmaf(v0f, (float)E_, u0f) - (O_ * E_ + O_);

        const uint2* p = base + idx;
        const uint2 T00 = p[0];
        const uint2 T01 = p[1];
        const uint2 T10 = p[E_];
        const uint2 T11 = p[E_ + 1];

        {   // batch 0: lo halves of .x
            const float top = fmaf(wu, bf_lo(T01.x) - bf_lo(T00.x), bf_lo(T00.x));
            const float bot = fmaf(wu, bf_lo(T11.x) - bf_lo(T10.x), bf_lo(T10.x));
            acc0 += fmaf(wvv, bot - top, top);
        }
        {   // batch 1: hi halves of .x
            const float top = fmaf(wu, bf_hi(T01.x) - bf_hi(T00.x), bf_hi(T00.x));
            const float bot = fmaf(wu, bf_hi(T11.x) - bf_hi(T10.x), bf_hi(T10.x));
            acc1 += fmaf(wvv, bot - top, top);
        }
        {   // batch 2: lo halves of .y
            const float top = fmaf(wu, bf_lo(T01.y) - bf_lo(T00.y), bf_lo(T00.y));
            const float bot = fmaf(wu, bf_lo(T11.y) - bf_lo(T10.y), bf_lo(T10.y));
            acc2 += fmaf(wvv, bot - top, top);
        }
        {   // batch 3: hi halves of .y
            const float top = fmaf(wu, bf_hi(T01.y) - bf_hi(T00.y), bf_hi(T00.y));
            const float bot = fmaf(wu, bf_hi(T11.y) - bf_hi(T10.y), bf_hi(T10.y));
            acc3 += fmaf(wvv, bot - top, top);
        }
    }

    // 4-step butterfly within each 16-lane group; 4 independent chains (ILP)
    #pragma unroll
    for (int m = 1; m <= 8; m <<= 1) {
        acc0 += __shfl_xor(acc0, m);
        acc1 += __shfl_xor(acc1, m);
        acc2 += __shfl_xor(acc2, m);
        acc3 += __shfl_xor(acc3, m);
    }

    if (l == 0 && y < P) {
        atomicAdd(&out[(0 * P + y) * NA + a], acc0 / 460.0f);
        atomicAdd(&out[(1 * P + y) * NA + a], acc1 / 460.0f);
        atomicAdd(&out[(2 * P + y) * NA + a], acc2 / 460.0f);
        atomicAdd(&out[(3 * P + y) * NA + a], acc3 / 460.0f);
    }
}

// ---- Fallback (no/undersized workspace): bounds-checked direct sampling ----
__device__ __forceinline__ float samp(const float* __restrict__ img, int iy, int ix) {
    unsigned uy = (unsigned)(iy - PAD);
    unsigned ux = (unsigned)(ix - PAD);
    return (uy < (unsigned)IMG && ux < (unsigned)IMG) ? img[uy * IMG + ux] : 0.0f;
}

__global__ __launch_bounds__(256) void radon_fallback(const float* __restrict__ x,
                                                      float* __restrict__ out) {
    const int wid  = blockIdx.x * 4 + (threadIdx.x >> 6);
    const int lane = threadIdx.x & 63;
    if (wid >= NB * NA * P) return;
    const int y  = wid % P;
    const int ba = wid / P;
    const int a  = ba % NA;
    const int b  = ba / NA;
    const float th = (2.8125f * (float)a) * 0.017453292519943295f;
    float s, c;
    __sincosf(th, &s, &c);
    const float ysy = (2.0f * (float)y + 1.0f) / 460.0f - 1.0f;
    const float* img = x + b * IMG * IMG;
    float acc = 0.0f;
    for (int xx = lane; xx < P; xx += 64) {
        const float xsx = (2.0f * (float)xx + 1.0f) / 460.0f - 1.0f;
        const float gx = c * xsx - s * ysy;
        const float gy = s * xsx + c * ysy;
        const float fix = ((gx + 1.0f) * 460.0f - 1.0f) * 0.5f;
        const float fiy = ((gy + 1.0f) * 460.0f - 1.0f) * 0.5f;
        const float ix0f = floorf(fix);
        const float iy0f = floorf(fiy);
        const float wx = fix - ix0f;
        const float wy = fiy - iy0f;
        const int ix0 = (int)ix0f;
        const int iy0 = (int)iy0f;
        const float v00 = samp(img, iy0,     ix0);
        const float v01 = samp(img, iy0,     ix0 + 1);
        const float v10 = samp(img, iy0 + 1, ix0);
        const float v11 = samp(img, iy0 + 1, ix0 + 1);
        acc += v00 * ((1.0f - wy) * (1.0f - wx))
             + v01 * ((1.0f - wy) * wx)
             + v10 * (wy * (1.0f - wx))
             + v11 * (wy * wx);
    }
    #pragma unroll
    for (int off = 32; off; off >>= 1) acc += __shfl_xor(acc, off);
    if (lane == 0) out[(b * P + y) * NA + a] = acc / 460.0f;
}

extern "C" void kernel_launch(void* const* d_in, const int* in_sizes, int n_in,
                              void* d_out, int out_size, void* d_ws, size_t ws_size,
                              hipStream_t stream) {
    const float* x = (const float*)d_in[0];
    float* out = (float*)d_out;

    const size_t layer = (size_t)E_ * E_;            // texels per layout
    const size_t need  = 2 * layer * sizeof(uint2);  // ~2.5 MB

    if (ws_size >= need) {
        uint2* pb  = (uint2*)d_ws;
        uint2* pbT = pb + layer;
        hipMemsetAsync(out, 0, (size_t)out_size * sizeof(float), stream);
        dim3 pgrid((E_ + 63) / 64, (E_ + 63) / 64);      // (7,7)
        pad4_kernel<<<pgrid, dim3(64, 4), 0, stream>>>(x, pb, pbT);
        dim3 grid((P + 15) / 16, NA, NSPLIT);            // (29, 64, 2)
        radon_kernel<<<grid, 256, 0, stream>>>(pb, pbT, out);
    } else {
        const int total_waves = NB * NA * P;
        const int blocks = (total_waves + 3) / 4;
        radon_fallback<<<blocks, 256, 0, stream>>>(x, out);
    }
}

// Round 8
// 31.954 us; speedup vs baseline: 1.2116x; 1.2116x over previous
//
#include <hip/hip_runtime.h>
#include <hip/hip_bf16.h>

// Radon transform: x (4,1,384,384) f32 -> out (4,460,64) f32
// pad = 38, Hp = Wp = 460, N_ANGLES = 64.
//
// R8: R6 structure (batch-interleaved bf16 texels: one aligned dwordx2 per
// bilinear corner serves all 4 batches; normal+transposed layouts, 2.5 MB,
// L2-resident; wave = 4y x 16xx lanes x 4 batches) with BLOCK = 128 (2 waves)
// instead of 256: 3712 blocks -> 14.5 blocks/CU (~29 waves/CU resident) vs
// R6's 7.25 4-wave blocks (one fill, immediate drain, 40% occupancy).
// No atomics, no memset, 2 dispatches total.

constexpr int IMG = 384;
constexpr int PAD = 38;
constexpr int P   = 460;   // Hp = Wp
constexpr int NA  = 64;
constexpr int NB  = 4;
constexpr int B_  = 6;               // zero border
constexpr int O_  = PAD - B_;        // 32
constexpr int E_  = IMG + 2 * B_;    // 396

__device__ __forceinline__ unsigned int f2bfu(float f) {
    __hip_bfloat16 h = __float2bfloat16(f);   // RNE
    return (unsigned int)__builtin_bit_cast(unsigned short, h);
}
__device__ __forceinline__ float bf_lo(unsigned int w) { return __uint_as_float(w << 16); }
__device__ __forceinline__ float bf_hi(unsigned int w) { return __uint_as_float(w & 0xffff0000u); }

// Pad + interleave batches + build normal and transposed layouts.
__global__ __launch_bounds__(256) void pad4_kernel(const float* __restrict__ x,
                                                   uint2* __restrict__ pb,
                                                   uint2* __restrict__ pbT) {
    __shared__ uint2 tile[64][65];
    const int tx = threadIdx.x;          // 0..63
    const int ty = threadIdx.y;          // 0..3
    const int bx = blockIdx.x * 64;
    const int by = blockIdx.y * 64;

    for (int r = ty; r < 64; r += 4) {
        const int iy = by + r, ix = bx + tx;
        const int py = iy - B_, px = ix - B_;       // core coords
        uint2 t = make_uint2(0u, 0u);
        if ((unsigned)py < (unsigned)IMG && (unsigned)px < (unsigned)IMG) {
            const int o = py * IMG + px;
            t.x = f2bfu(x[o])                 | (f2bfu(x[IMG * IMG + o])     << 16);
            t.y = f2bfu(x[2 * IMG * IMG + o]) | (f2bfu(x[3 * IMG * IMG + o]) << 16);
        }
        tile[r][tx] = t;
        if (iy < E_ && ix < E_) pb[iy * E_ + ix] = t;
    }
    __syncthreads();
    for (int r = ty; r < 64; r += 4) {
        const int oy = bx + r;           // transposed row = original col
        const int ox = by + tx;
        if (oy < E_ && ox < E_) pbT[oy * E_ + ox] = tile[tx][r];
    }
}

__global__ __launch_bounds__(128) void radon_kernel(const uint2* __restrict__ pb,
                                                    const uint2* __restrict__ pbT,
                                                    float* __restrict__ out) {
    const int lane = threadIdx.x & 63;
    const int wv   = threadIdx.x >> 6;       // 0..1
    const int l    = lane & 15;              // lane in group
    const int g    = lane >> 4;              // y-group in wave
    const int a    = blockIdx.y;
    const int y    = blockIdx.x * 8 + wv * 4 + g;

    const float th = (2.8125f * (float)a) * 0.017453292519943295f;
    float s, c;
    __sincosf(th, &s, &c);

    const float yf = (float)(y < P ? y : P - 1);
    const float ys = (2.0f * yf + 1.0f) / 460.0f - 1.0f;
    // fix = c*xx + A ; fiy = s*xx + By (padded-image pixel coords)
    const float A  = fmaf(-s, ys, 1.0f) * 230.0f - 0.5f - 229.5f * c;
    const float By = fmaf( c, ys, 1.0f) * 230.0f - 0.5f - 229.5f * s;

    // xx-interval where the stencil can touch the core ([36,424] conservative;
    // rcp error + floor slack covered by +/-2 and the 6px border).
    const float rc = __builtin_amdgcn_rcpf(c);
    const float rs = __builtin_amdgcn_rcpf(s);
    float t0 = (36.0f - A) * rc, t1 = (424.0f - A) * rc;
    float lo = fmaxf(0.0f,   fminf(t0, t1));
    float hi = fminf(459.0f, fmaxf(t0, t1));
    t0 = (36.0f - By) * rs; t1 = (424.0f - By) * rs;
    lo = fmaxf(lo, fminf(t0, t1));
    hi = fminf(hi, fmaxf(t0, t1));

    int glo = max(0, (int)floorf(lo) - 2);
    glo = min(glo, P);                       // saturate +inf case, avoid wrap
    int ghi = min(P - 1, (int)ceilf(hi) + 2);
    if (y >= P) { glo = 1; ghi = 0; }

    // Layout: row coord v should step slowly with xx -> |cv| = min(|c|,|s|).
    const bool  useT = fabsf(s) > fabsf(c);
    const float cu = useT ? s  : c;
    const float Au = useT ? By : A;
    const float cv = useT ? c  : s;
    const float Av = useT ? A  : By;
    const uint2* __restrict__ base = useT ? pbT : pb;

    float acc0 = 0.0f, acc1 = 0.0f, acc2 = 0.0f, acc3 = 0.0f;
    float xxf = (float)(glo + l);
    #pragma unroll 2
    for (int xx = glo + l; xx <= ghi; xx += 16, xxf += 16.0f) {
        const float u   = fmaf(cu, xxf, Au);
        const float v   = fmaf(cv, xxf, Av);
        const float u0f = floorf(u);
        const float v0f = floorf(v);
        const float wu  = u - u0f;
        const float wvv = v - v0f;
        const int idx = (int)fmaf(v0f, (float)E_, u0f) - (O_ * E_ + O_);

        const uint2* p = base + idx;
        const uint2 T00 = p[0];
        const uint2 T01 = p[1];
        const uint2 T10 = p[E_];
        const uint2 T11 = p[E_ + 1];

        {   // batch 0: lo halves of .x
            const float top = fmaf(wu, bf_lo(T01.x) - bf_lo(T00.x), bf_lo(T00.x));
            const float bot = fmaf(wu, bf_lo(T11.x) - bf_lo(T10.x), bf_lo(T10.x));
            acc0 += fmaf(wvv, bot - top, top);
        }
        {   // batch 1: hi halves of .x
            const float top = fmaf(wu, bf_hi(T01.x) - bf_hi(T00.x), bf_hi(T00.x));
            const float bot = fmaf(wu, bf_hi(T11.x) - bf_hi(T10.x), bf_hi(T10.x));
            acc1 += fmaf(wvv, bot - top, top);
        }
        {   // batch 2: lo halves of .y
            const float top = fmaf(wu, bf_lo(T01.y) - bf_lo(T00.y), bf_lo(T00.y));
            const float bot = fmaf(wu, bf_lo(T11.y) - bf_lo(T10.y), bf_lo(T10.y));
            acc2 += fmaf(wvv, bot - top, top);
        }
        {   // batch 3: hi halves of .y
            const float top = fmaf(wu, bf_hi(T01.y) - bf_hi(T00.y), bf_hi(T00.y));
            const float bot = fmaf(wu, bf_hi(T11.y) - bf_hi(T10.y), bf_hi(T10.y));
            acc3 += fmaf(wvv, bot - top, top);
        }
    }

    // 4-step butterfly within each 16-lane group; 4 independent chains (ILP)
    #pragma unroll
    for (int m = 1; m <= 8; m <<= 1) {
        acc0 += __shfl_xor(acc0, m);
        acc1 += __shfl_xor(acc1, m);
        acc2 += __shfl_xor(acc2, m);
        acc3 += __shfl_xor(acc3, m);
    }

    if (l == 0 && y < P) {
        out[(0 * P + y) * NA + a] = acc0 / 460.0f;
        out[(1 * P + y) * NA + a] = acc1 / 460.0f;
        out[(2 * P + y) * NA + a] = acc2 / 460.0f;
        out[(3 * P + y) * NA + a] = acc3 / 460.0f;
    }
}

// ---- Fallback (no/undersized workspace): bounds-checked direct sampling ----
__device__ __forceinline__ float samp(const float* __restrict__ img, int iy, int ix) {
    unsigned uy = (unsigned)(iy - PAD);
    unsigned ux = (unsigned)(ix - PAD);
    return (uy < (unsigned)IMG && ux < (unsigned)IMG) ? img[uy * IMG + ux] : 0.0f;
}

__global__ __launch_bounds__(256) void radon_fallback(const float* __restrict__ x,
                                                      float* __restrict__ out) {
    const int wid  = blockIdx.x * 4 + (threadIdx.x >> 6);
    const int lane = threadIdx.x & 63;
    if (wid >= NB * NA * P) return;
    const int y  = wid % P;
    const int ba = wid / P;
    const int a  = ba % NA;
    const int b  = ba / NA;
    const float th = (2.8125f * (float)a) * 0.017453292519943295f;
    float s, c;
    __sincosf(th, &s, &c);
    const float ysy = (2.0f * (float)y + 1.0f) / 460.0f - 1.0f;
    const float* img = x + b * IMG * IMG;
    float acc = 0.0f;
    for (int xx = lane; xx < P; xx += 64) {
        const float xsx = (2.0f * (float)xx + 1.0f) / 460.0f - 1.0f;
        const float gx = c * xsx - s * ysy;
        const float gy = s * xsx + c * ysy;
        const float fix = ((gx + 1.0f) * 460.0f - 1.0f) * 0.5f;
        const float fiy = ((gy + 1.0f) * 460.0f - 1.0f) * 0.5f;
        const float ix0f = floorf(fix);
        const float iy0f = floorf(fiy);
        const float wx = fix - ix0f;
        const float wy = fiy - iy0f;
        const int ix0 = (int)ix0f;
        const int iy0 = (int)iy0f;
        const float v00 = samp(img, iy0,     ix0);
        const float v01 = samp(img, iy0,     ix0 + 1);
        const float v10 = samp(img, iy0 + 1, ix0);
        const float v11 = samp(img, iy0 + 1, ix0 + 1);
        acc += v00 * ((1.0f - wy) * (1.0f - wx))
             + v01 * ((1.0f - wy) * wx)
             + v10 * (wy * (1.0f - wx))
             + v11 * (wy * wx);
    }
    #pragma unroll
    for (int off = 32; off; off >>= 1) acc += __shfl_xor(acc, off);
    if (lane == 0) out[(b * P + y) * NA + a] = acc / 460.0f;
}

extern "C" void kernel_launch(void* const* d_in, const int* in_sizes, int n_in,
                              void* d_out, int out_size, void* d_ws, size_t ws_size,
                              hipStream_t stream) {
    const float* x = (const float*)d_in[0];
    float* out = (float*)d_out;

    const size_t layer = (size_t)E_ * E_;            // texels per layout
    const size_t need  = 2 * layer * sizeof(uint2);  // ~2.5 MB

    if (ws_size >= need) {
        uint2* pb  = (uint2*)d_ws;
        uint2* pbT = pb + layer;
        dim3 pgrid((E_ + 63) / 64, (E_ + 63) / 64);      // (7,7)
        pad4_kernel<<<pgrid, dim3(64, 4), 0, stream>>>(x, pb, pbT);
        dim3 grid((P + 7) / 8, NA);                      // (58, 64) x 2-wave blocks
        radon_kernel<<<grid, 128, 0, stream>>>(pb, pbT, out);
    } else {
        const int total_waves = NB * NA * P;
        const int blocks = (total_waves + 3) / 4;
        radon_fallback<<<blocks, 256, 0, stream>>>(x, out);
    }
}

// Round 9
// 28.938 us; speedup vs baseline: 1.3379x; 1.1042x over previous
//
#include <hip/hip_runtime.h>
#include <hip/hip_bf16.h>

// Radon transform: x (4,1,384,384) f32 -> out (4,460,64) f32
// pad = 38, Hp = Wp = 460, N_ANGLES = 64.
//
// R9: R8 structure (batch-interleaved bf16 texels, normal+transposed layouts
// L2-resident, wave = 4y x 16xx x 4 batches, 128-thread blocks) with
//  (a) stencil-ROW loads: one uint4 (dwordx4, 8B-aligned) per bilinear row
//      -> 2 load instructions/iter instead of 4 (halves L1 line re-touches);
//  (b) 1D pad kernel, 613 blocks (R8's tiled version ran only 49 blocks,
//      latency-starved); pbT scatter writes absorbed by L2.

constexpr int IMG = 384;
constexpr int PAD = 38;
constexpr int P   = 460;   // Hp = Wp
constexpr int NA  = 64;
constexpr int NB  = 4;
constexpr int B_  = 6;               // zero border
constexpr int O_  = PAD - B_;        // 32
constexpr int E_  = IMG + 2 * B_;    // 396

__device__ __forceinline__ unsigned int f2bfu(float f) {
    __hip_bfloat16 h = __float2bfloat16(f);   // RNE
    return (unsigned int)__builtin_bit_cast(unsigned short, h);
}
__device__ __forceinline__ float bf_lo(unsigned int w) { return __uint_as_float(w << 16); }
__device__ __forceinline__ float bf_hi(unsigned int w) { return __uint_as_float(w & 0xffff0000u); }

// 1D pad + batch-interleave + both layouts. One thread per texel position.
__global__ __launch_bounds__(256) void pad4_kernel(const float* __restrict__ x,
                                                   uint2* __restrict__ pb,
                                                   uint2* __restrict__ pbT) {
    const int idx = blockIdx.x * 256 + threadIdx.x;
    if (idx >= E_ * E_) return;
    const int iy = idx / E_;
    const int ix = idx - iy * E_;
    const int py = iy - B_, px = ix - B_;       // core coords
    uint2 t = make_uint2(0u, 0u);
    if ((unsigned)py < (unsigned)IMG && (unsigned)px < (unsigned)IMG) {
        const int o = py * IMG + px;
        t.x = f2bfu(x[o])                 | (f2bfu(x[IMG * IMG + o])     << 16);
        t.y = f2bfu(x[2 * IMG * IMG + o]) | (f2bfu(x[3 * IMG * IMG + o]) << 16);
    }
    pb[iy * E_ + ix]  = t;      // coalesced
    pbT[ix * E_ + iy] = t;      // scattered 8B; L2 absorbs (1.25 MB total)
}

__global__ __launch_bounds__(128) void radon_kernel(const uint2* __restrict__ pb,
                                                    const uint2* __restrict__ pbT,
                                                    float* __restrict__ out) {
    const int lane = threadIdx.x & 63;
    const int wv   = threadIdx.x >> 6;       // 0..1
    const int l    = lane & 15;              // lane in group
    const int g    = lane >> 4;              // y-group in wave
    const int a    = blockIdx.y;
    const int y    = blockIdx.x * 8 + wv * 4 + g;

    const float th = (2.8125f * (float)a) * 0.017453292519943295f;
    float s, c;
    __sincosf(th, &s, &c);

    const float yf = (float)(y < P ? y : P - 1);
    const float ys = (2.0f * yf + 1.0f) / 460.0f - 1.0f;
    // fix = c*xx + A ; fiy = s*xx + By (padded-image pixel coords)
    const float A  = fmaf(-s, ys, 1.0f) * 230.0f - 0.5f - 229.5f * c;
    const float By = fmaf( c, ys, 1.0f) * 230.0f - 0.5f - 229.5f * s;

    // xx-interval where the stencil can touch the core ([36,424] conservative;
    // rcp error + floor slack covered by +/-2 and the 6px border).
    const float rc = __builtin_amdgcn_rcpf(c);
    const float rs = __builtin_amdgcn_rcpf(s);
    float t0 = (36.0f - A) * rc, t1 = (424.0f - A) * rc;
    float lo = fmaxf(0.0f,   fminf(t0, t1));
    float hi = fminf(459.0f, fmaxf(t0, t1));
    t0 = (36.0f - By) * rs; t1 = (424.0f - By) * rs;
    lo = fmaxf(lo, fminf(t0, t1));
    hi = fminf(hi, fmaxf(t0, t1));

    int glo = max(0, (int)floorf(lo) - 2);
    glo = min(glo, P);                       // saturate +inf case, avoid wrap
    int ghi = min(P - 1, (int)ceilf(hi) + 2);
    if (y >= P) { glo = 1; ghi = 0; }

    // Layout: row coord v should step slowly with xx -> |cv| = min(|c|,|s|).
    const bool  useT = fabsf(s) > fabsf(c);
    const float cu = useT ? s  : c;
    const float Au = useT ? By : A;
    const float cv = useT ? c  : s;
    const float Av = useT ? A  : By;
    const uint2* __restrict__ base = useT ? pbT : pb;

    float acc0 = 0.0f, acc1 = 0.0f, acc2 = 0.0f, acc3 = 0.0f;
    float xxf = (float)(glo + l);
    #pragma unroll 2
    for (int xx = glo + l; xx <= ghi; xx += 16, xxf += 16.0f) {
        const float u   = fmaf(cu, xxf, Au);
        const float v   = fmaf(cv, xxf, Av);
        const float u0f = floorf(u);
        const float v0f = floorf(v);
        const float wu  = u - u0f;
        const float wvv = v - v0f;
        const int idx = (int)fmaf(v0f, (float)E_, u0f) - (O_ * E_ + O_);

        // One 16B load per stencil row: texels (u0,v) and (u0+1,v).
        // 8B-aligned dwordx4 — gfx9+ global loads need only 4B alignment.
        const uint4 R0 = *reinterpret_cast<const uint4*>(base + idx);
        const uint4 R1 = *reinterpret_cast<const uint4*>(base + idx + E_);

        {   // batch 0: lo halves of words 0 (u0) and 2 (u0+1)
            const float top = fmaf(wu, bf_lo(R0.z) - bf_lo(R0.x), bf_lo(R0.x));
            const float bot = fmaf(wu, bf_lo(R1.z) - bf_lo(R1.x), bf_lo(R1.x));
            acc0 += fmaf(wvv, bot - top, top);
        }
        {   // batch 1: hi halves of words 0/2
            const float top = fmaf(wu, bf_hi(R0.z) - bf_hi(R0.x), bf_hi(R0.x));
            const float bot = fmaf(wu, bf_hi(R1.z) - bf_hi(R1.x), bf_hi(R1.x));
            acc1 += fmaf(wvv, bot - top, top);
        }
        {   // batch 2: lo halves of words 1/3
            const float top = fmaf(wu, bf_lo(R0.w) - bf_lo(R0.y), bf_lo(R0.y));
            const float bot = fmaf(wu, bf_lo(R1.w) - bf_lo(R1.y), bf_lo(R1.y));
            acc2 += fmaf(wvv, bot - top, top);
        }
        {   // batch 3: hi halves of words 1/3
            const float top = fmaf(wu, bf_hi(R0.w) - bf_hi(R0.y), bf_hi(R0.y));
            const float bot = fmaf(wu, bf_hi(R1.w) - bf_hi(R1.y), bf_hi(R1.y));
            acc3 += fmaf(wvv, bot - top, top);
        }
    }

    // 4-step butterfly within each 16-lane group; 4 independent chains (ILP)
    #pragma unroll
    for (int m = 1; m <= 8; m <<= 1) {
        acc0 += __shfl_xor(acc0, m);
        acc1 += __shfl_xor(acc1, m);
        acc2 += __shfl_xor(acc2, m);
        acc3 += __shfl_xor(acc3, m);
    }

    if (l == 0 && y < P) {
        out[(0 * P + y) * NA + a] = acc0 / 460.0f;
        out[(1 * P + y) * NA + a] = acc1 / 460.0f;
        out[(2 * P + y) * NA + a] = acc2 / 460.0f;
        out[(3 * P + y) * NA + a] = acc3 / 460.0f;
    }
}

// ---- Fallback (no/undersized workspace): bounds-checked direct sampling ----
__device__ __forceinline__ float samp(const float* __restrict__ img, int iy, int ix) {
    unsigned uy = (unsigned)(iy - PAD);
    unsigned ux = (unsigned)(ix - PAD);
    return (uy < (unsigned)IMG && ux < (unsigned)IMG) ? img[uy * IMG + ux] : 0.0f;
}

__global__ __launch_bounds__(256) void radon_fallback(const float* __restrict__ x,
                                                      float* __restrict__ out) {
    const int wid  = blockIdx.x * 4 + (threadIdx.x >> 6);
    const int lane = threadIdx.x & 63;
    if (wid >= NB * NA * P) return;
    const int y  = wid % P;
    const int ba = wid / P;
    const int a  = ba % NA;
    const int b  = ba / NA;
    const float th = (2.8125f * (float)a) * 0.017453292519943295f;
    float s, c;
    __sincosf(th, &s, &c);
    const float ysy = (2.0f * (float)y + 1.0f) / 460.0f - 1.0f;
    const float* img = x + b * IMG * IMG;
    float acc = 0.0f;
    for (int xx = lane; xx < P; xx += 64) {
        const float xsx = (2.0f * (float)xx + 1.0f) / 460.0f - 1.0f;
        const float gx = c * xsx - s * ysy;
        const float gy = s * xsx + c * ysy;
        const float fix = ((gx + 1.0f) * 460.0f - 1.0f) * 0.5f;
        const float fiy = ((gy + 1.0f) * 460.0f - 1.0f) * 0.5f;
        const float ix0f = floorf(fix);
        const float iy0f = floorf(fiy);
        const float wx = fix - ix0f;
        const float wy = fiy - iy0f;
        const int ix0 = (int)ix0f;
        const int iy0 = (int)iy0f;
        const float v00 = samp(img, iy0,     ix0);
        const float v01 = samp(img, iy0,     ix0 + 1);
        const float v10 = samp(img, iy0 + 1, ix0);
        const float v11 = samp(img, iy0 + 1, ix0 + 1);
        acc += v00 * ((1.0f - wy) * (1.0f - wx))
             + v01 * ((1.0f - wy) * wx)
             + v10 * (wy * (1.0f - wx))
             + v11 * (wy * wx);
    }
    #pragma unroll
    for (int off = 32; off; off >>= 1) acc += __shfl_xor(acc, off);
    if (lane == 0) out[(b * P + y) * NA + a] = acc / 460.0f;
}

extern "C" void kernel_launch(void* const* d_in, const int* in_sizes, int n_in,
                              void* d_out, int out_size, void* d_ws, size_t ws_size,
                              hipStream_t stream) {
    const float* x = (const float*)d_in[0];
    float* out = (float*)d_out;

    const size_t layer = (size_t)E_ * E_;            // texels per layout
    const size_t need  = 2 * layer * sizeof(uint2);  // ~2.5 MB

    if (ws_size >= need) {
        uint2* pb  = (uint2*)d_ws;
        uint2* pbT = pb + layer;
        const int pad_blocks = (E_ * E_ + 255) / 256;    // 613
        pad4_kernel<<<pad_blocks, 256, 0, stream>>>(x, pb, pbT);
        dim3 grid((P + 7) / 8, NA);                      // (58, 64) x 2-wave blocks
        radon_kernel<<<grid, 128, 0, stream>>>(pb, pbT, out);
    } else {
        const int total_waves = NB * NA * P;
        const int blocks = (total_waves + 3) / 4;
        radon_fallback<<<blocks, 256, 0, stream>>>(x, out);
    }
}